// Round 2
// baseline (317.928 us; speedup 1.0000x reference)
//
#include <hip/hip_runtime.h>
#include <hip/hip_bf16.h>

typedef __attribute__((ext_vector_type(8))) short short8;   // 8 x bf16 (4 VGPRs) MFMA frag
typedef __attribute__((ext_vector_type(4))) float f32x4;    // MFMA accumulator
typedef __attribute__((ext_vector_type(4))) unsigned short us4;

#define GK 1024   // K dim of both GEMMs (= word dim)

// ---------- helpers ----------
__device__ __forceinline__ unsigned short f2bf(float f) {       // RNE f32->bf16
  unsigned int u = __float_as_uint(f);
  u += 0x7fffu + ((u >> 16) & 1u);
  return (unsigned short)(u >> 16);
}

__device__ __forceinline__ void gload16(const void* g, void* lds_base /*wave-uniform*/) {
  __builtin_amdgcn_global_load_lds(
      (const __attribute__((address_space(1))) unsigned int*)g,
      (__attribute__((address_space(3))) unsigned int*)lds_base, 16, 0, 0);
}

// ---------- kernel 1: cast f32 -> bf16 (x) ----------
__global__ void cast4_f32_bf16(const float* __restrict__ in, unsigned short* __restrict__ out, int n) {
  int i = (blockIdx.x * 256 + threadIdx.x) * 4;
  if (i >= n) return;
  float4 v = *(const float4*)(in + i);
  us4 o = { f2bf(v.x), f2bf(v.y), f2bf(v.z), f2bf(v.w) };
  *(us4*)(out + i) = o;
}

// ---------- kernel 2: transpose+cast W[K][N] f32 -> Wt[N][K] bf16 ----------
__global__ void transcast(const float* __restrict__ in, unsigned short* __restrict__ out, int K, int N) {
  __shared__ float t[32][33];
  int n0 = blockIdx.x * 32, k0 = blockIdx.y * 32;
  int tx = threadIdx.x, ty = threadIdx.y;
#pragma unroll
  for (int i = 0; i < 4; ++i)
    t[ty * 4 + i][tx] = in[(size_t)(k0 + ty * 4 + i) * N + n0 + tx];
  __syncthreads();
#pragma unroll
  for (int i = 0; i < 4; ++i)
    out[(size_t)(n0 + ty * 4 + i) * K + k0 + tx] = f2bf(t[tx][ty * 4 + i]);
}

// ---------- GEMM (NT): C[M][N] = A[M][1024] * Bt[N][1024]^T + bias ----------
// 128x128 tile, BK=32, 4 waves (2x2), 16x16x32 bf16 MFMA, global_load_lds staging (m97 structure)
template <int OUT_BF16>
__global__ __launch_bounds__(256) void gemm_nt(
    const unsigned short* __restrict__ A,
    const unsigned short* __restrict__ Bt,
    const float* __restrict__ bias,
    void* __restrict__ C, int M, int N)
{
  __shared__ __align__(16) unsigned short Asm[128 * 32];
  __shared__ __align__(16) unsigned short Bsm[128 * 32];
  int bm = blockIdx.x, bn = blockIdx.y;
  int t = threadIdx.x, w = t >> 6, l = t & 63;
  int wm = w >> 1, wn = w & 1;
  int g = l >> 4, ln = l & 15;

  const unsigned short* Ablk = A + (size_t)(bm * 128) * GK;
  const unsigned short* Bblk = Bt + (size_t)(bn * 128) * GK;

  f32x4 acc[4][4] = {};

  int r0 = (w << 4) + (l >> 2);      // staging row within chunk group
  int kc = (l & 3) * 8;              // staging k offset (elems)

  for (int kt = 0; kt < GK / 32; ++kt) {
    __syncthreads();
    int k0 = kt * 32 + kc;
    // A tile: chunks w and w+4 (each chunk = 16 rows x 32 k = 1KB)
    gload16(Ablk + (size_t)r0 * GK + k0,        Asm + w * 512);
    gload16(Ablk + (size_t)(r0 + 64) * GK + k0, Asm + (4 + w) * 512);
    gload16(Bblk + (size_t)r0 * GK + k0,        Bsm + w * 512);
    gload16(Bblk + (size_t)(r0 + 64) * GK + k0, Bsm + (4 + w) * 512);
    __syncthreads();

    short8 af[4], bf[4];
    int ar = wm * 64 + ln;
    int br = wn * 64 + ln;
    int kk = g * 8;
#pragma unroll
    for (int mt = 0; mt < 4; ++mt)
      af[mt] = *(const short8*)(Asm + (ar + mt * 16) * 32 + kk);
#pragma unroll
    for (int nt = 0; nt < 4; ++nt)
      bf[nt] = *(const short8*)(Bsm + (br + nt * 16) * 32 + kk);
#pragma unroll
    for (int mt = 0; mt < 4; ++mt)
#pragma unroll
      for (int nt = 0; nt < 4; ++nt)
        acc[mt][nt] = __builtin_amdgcn_mfma_f32_16x16x32_bf16(af[mt], bf[nt], acc[mt][nt], 0, 0, 0);
  }

  // epilogue: C/D layout col = lane&15, row = (lane>>4)*4 + reg (verified m89/m91)
  int rowb = bm * 128 + wm * 64 + (g << 2);
  int colb = bn * 128 + wn * 64 + ln;
#pragma unroll
  for (int nt = 0; nt < 4; ++nt) {
    int col = colb + nt * 16;
    float bv = bias[col];
#pragma unroll
    for (int mt = 0; mt < 4; ++mt) {
      int row = rowb + mt * 16;
#pragma unroll
      for (int r = 0; r < 4; ++r) {
        float v = acc[mt][nt][r] + bv;
        if (OUT_BF16) ((unsigned short*)C)[(size_t)(row + r) * N + col] = f2bf(v);
        else          ((float*)C)[(size_t)(row + r) * N + col] = v;
      }
    }
  }
}

// ---------- kernel: transpose V slice of qkv -> Vt[(b*16+h)*64 + d][S] ----------
__global__ void transpose_v(const unsigned short* __restrict__ qkvb, unsigned short* __restrict__ Vt) {
  __shared__ __align__(16) unsigned short tile[64][72];   // [s][d], padded
  int blk = blockIdx.x;              // (b*16+h)*16 + s_tile
  int st = blk & 15, bh = blk >> 4, h = bh & 15, b = bh >> 4;
  int t = threadIdx.x;
  int srow = t >> 2, c0 = (t & 3) * 2;

  const unsigned short* src = qkvb + (size_t)(b * 1024 + st * 64 + srow) * 3072 + 2048 + h * 64;
#pragma unroll
  for (int j = 0; j < 2; ++j)
    *(short8*)(&tile[srow][(c0 + j) * 8]) = *(const short8*)(src + (c0 + j) * 8);
  __syncthreads();

  int d = t >> 2;
  unsigned short* dst = Vt + (size_t)(bh * 64 + d) * 1024 + st * 64;
#pragma unroll
  for (int j = 0; j < 2; ++j) {
    int s0 = (c0 + j) * 8;
    short8 v;
#pragma unroll
    for (int i = 0; i < 8; ++i) v[i] = tile[s0 + i][d];
    *(short8*)(dst + s0) = v;
  }
}

// ---------- flash attention v2: wave-independent, no barriers, K/V direct from L2 ----------
// Each wave owns TWO 16-row q-tiles (pair p and 63-p) -> constant ~17 kt-iters per wave.
// Grid: bh*8 + pb (1024 blocks, 4 waves each). LDS: per-wave P transpose buffer only.
__global__ __launch_bounds__(256) void attn(
    const unsigned short* __restrict__ qkv,  // [8192][3072] bf16
    const unsigned short* __restrict__ Vt,   // [(b*16+h)*64 + d][1024] bf16
    unsigned short* __restrict__ Ob)         // [8192][1024] bf16
{
  __shared__ __align__(16) unsigned short Psm[4][16 * 64]; // per-wave P [qrow][key] (swizzled)

  int t = threadIdx.x, w = t >> 6, l = t & 63;
  int g = l >> 4, ln = l & 15;
  int blk = blockIdx.x;                    // bh*8 + pb
  int pb = blk & 7, bh = blk >> 3, h = bh & 15, b = bh >> 4;
  int pair = pb * 4 + w;                   // 0..31

  const unsigned short* Kg = qkv + (size_t)(b * 1024) * 3072 + 1024 + h * 64;
  const unsigned short* Vg = Vt + (size_t)(bh * 64) * 1024;
  unsigned short* P = Psm[w];

#pragma unroll
  for (int half = 0; half < 2; ++half) {
    int qt16 = half ? (63 - pair) : pair;  // 16-row q-tile index 0..63

    // Q fragments: A[row=ln][k = 8g+e (+32)]
    const unsigned short* qbase =
        qkv + (size_t)(b * 1024 + qt16 * 16 + ln) * 3072 + h * 64 + g * 8;
    short8 qf0 = *(const short8*)(qbase);
    short8 qf1 = *(const short8*)(qbase + 32);

    f32x4 acc_o[4] = {};
    float m_r[4], l_r[4];
#pragma unroll
    for (int r = 0; r < 4; ++r) { m_r[r] = -3.0e38f; l_r[r] = 0.f; }

    int ktmax = qt16 >> 2;
    for (int kt = 0; kt <= ktmax; ++kt) {
      // S = Q K^T  (M=16 q rows, N=64 keys, K=dh 64) — K direct from global (L2-resident)
      f32x4 s[4] = {};
#pragma unroll
      for (int nt = 0; nt < 4; ++nt) {
        const unsigned short* kr = Kg + (size_t)(kt * 64 + nt * 16 + ln) * 3072 + g * 8;
        short8 b0 = *(const short8*)(kr);
        short8 b1 = *(const short8*)(kr + 32);
        s[nt] = __builtin_amdgcn_mfma_f32_16x16x32_bf16(qf0, b0, s[nt], 0, 0, 0);
        s[nt] = __builtin_amdgcn_mfma_f32_16x16x32_bf16(qf1, b1, s[nt], 0, 0, 0);
      }

      // scale + causal mask (exactly -1e9 like the reference additive mask)
      bool diag = (kt == ktmax);
#pragma unroll
      for (int nt = 0; nt < 4; ++nt)
#pragma unroll
        for (int r = 0; r < 4; ++r) {
          float v = s[nt][r] * 0.125f;
          if (diag && (kt * 64 + nt * 16 + ln > qt16 * 16 + g * 4 + r)) v = -1.0e9f;
          s[nt][r] = v;
        }

      // online softmax; row (g*4+r) spread across the 16 lanes of group g
#pragma unroll
      for (int r = 0; r < 4; ++r) {
        float mx = fmaxf(fmaxf(s[0][r], s[1][r]), fmaxf(s[2][r], s[3][r]));
#pragma unroll
        for (int off = 8; off >= 1; off >>= 1) mx = fmaxf(mx, __shfl_xor(mx, off, 64));
        float mnew = fmaxf(m_r[r], mx);
        float corr = __expf(m_r[r] - mnew);
        m_r[r] = mnew;
        float rs = 0.f;
#pragma unroll
        for (int nt = 0; nt < 4; ++nt) {
          float p = __expf(s[nt][r] - mnew);
          s[nt][r] = p;
          rs += p;
        }
#pragma unroll
        for (int off = 8; off >= 1; off >>= 1) rs += __shfl_xor(rs, off, 64);
        l_r[r] = l_r[r] * corr + rs;
#pragma unroll
        for (int nt = 0; nt < 4; ++nt) acc_o[nt][r] *= corr;
      }

      // P (bf16) -> per-wave swizzled LDS (wave-local, no barrier), read back as A-frags
#pragma unroll
      for (int nt = 0; nt < 4; ++nt) {
        int col = nt * 16 + ln;
#pragma unroll
        for (int r = 0; r < 4; ++r) {
          int prow = g * 4 + r;
          P[prow * 64 + (((col >> 3) ^ (prow & 7)) * 8) + (col & 7)] = f2bf(s[nt][r]);
        }
      }
      short8 pa[2];
#pragma unroll
      for (int ks = 0; ks < 2; ++ks)
        pa[ks] = *(const short8*)(P + ln * 64 + ((((ks * 4) + g) ^ (ln & 7)) * 8));

      // PV: B = Vt[d][key] direct from global (L2-resident)
#pragma unroll
      for (int nt = 0; nt < 4; ++nt) {
        const unsigned short* vr = Vg + (size_t)(nt * 16 + ln) * 1024 + kt * 64 + g * 8;
        short8 vb0 = *(const short8*)(vr);
        short8 vb1 = *(const short8*)(vr + 32);
        acc_o[nt] = __builtin_amdgcn_mfma_f32_16x16x32_bf16(pa[0], vb0, acc_o[nt], 0, 0, 0);
        acc_o[nt] = __builtin_amdgcn_mfma_f32_16x16x32_bf16(pa[1], vb1, acc_o[nt], 0, 0, 0);
      }
    }

    // normalize + store
    float inv[4];
#pragma unroll
    for (int r = 0; r < 4; ++r) inv[r] = 1.0f / l_r[r];
    int orow = b * 1024 + qt16 * 16;
#pragma unroll
    for (int nt = 0; nt < 4; ++nt) {
      int col = h * 64 + nt * 16 + ln;
#pragma unroll
      for (int r = 0; r < 4; ++r)
        Ob[(size_t)(orow + g * 4 + r) * 1024 + col] = f2bf(acc_o[nt][r] * inv[r]);
    }
  }
}

// ---------- launcher ----------
extern "C" void kernel_launch(void* const* d_in, const int* in_sizes, int n_in,
                              void* d_out, int out_size, void* d_ws, size_t ws_size,
                              hipStream_t stream) {
  (void)in_sizes; (void)n_in; (void)out_size; (void)ws_size;
  const float* x    = (const float*)d_in[0];
  const float* Wqkv = (const float*)d_in[1];
  const float* bqkv = (const float*)d_in[2];
  const float* Wout = (const float*)d_in[3];
  const float* bout = (const float*)d_in[4];

  char* ws = (char*)d_ws;
  unsigned short* xb   = (unsigned short*)(ws);                 // 16 MB  [8192][1024]
  unsigned short* Wt1  = (unsigned short*)(ws + 16777216);      //  6 MB  [3072][1024]
  unsigned short* Wt2  = (unsigned short*)(ws + 23068672);      //  2 MB  [1024][1024]
  unsigned short* qkvb = (unsigned short*)(ws + 25165824);      // 50 MB  [8192][3072]
  unsigned short* Vt   = (unsigned short*)(ws + 75497472);      // 16 MB  [128*64][1024]
  unsigned short* Ob   = (unsigned short*)(ws + 92274688);      // 16 MB  [8192][1024]

  cast4_f32_bf16<<<8192, 256, 0, stream>>>(x, xb, 8192 * 1024);
  transcast<<<dim3(96, 32), dim3(32, 8), 0, stream>>>(Wqkv, Wt1, 1024, 3072);
  transcast<<<dim3(32, 32), dim3(32, 8), 0, stream>>>(Wout, Wt2, 1024, 1024);

  gemm_nt<1><<<dim3(64, 24), 256, 0, stream>>>(xb, Wt1, bqkv, qkvb, 8192, 3072);
  transpose_v<<<2048, 256, 0, stream>>>(qkvb, Vt);
  attn<<<1024, 256, 0, stream>>>(qkvb, Vt, Ob);
  gemm_nt<0><<<dim3(64, 8), 256, 0, stream>>>(Ob, Wt2, bout, (float*)d_out, 8192, 1024);
}

// Round 3
// 265.652 us; speedup vs baseline: 1.1968x; 1.1968x over previous
//
#include <hip/hip_runtime.h>
#include <hip/hip_bf16.h>

typedef __attribute__((ext_vector_type(8))) short short8;   // 8 x bf16 (4 VGPRs) MFMA frag
typedef __attribute__((ext_vector_type(4))) float f32x4;    // MFMA accumulator
typedef __attribute__((ext_vector_type(4))) unsigned short us4;

#define GK 1024   // K dim of both GEMMs (= word dim)

// ---------- helpers ----------
__device__ __forceinline__ unsigned short f2bf(float f) {       // RNE f32->bf16
  unsigned int u = __float_as_uint(f);
  u += 0x7fffu + ((u >> 16) & 1u);
  return (unsigned short)(u >> 16);
}

__device__ __forceinline__ void gload16(const void* g, void* lds_base /*wave-uniform*/) {
  __builtin_amdgcn_global_load_lds(
      (const __attribute__((address_space(1))) unsigned int*)g,
      (__attribute__((address_space(3))) unsigned int*)lds_base, 16, 0, 0);
}

// ---------- kernel 1: cast f32 -> bf16 (x) ----------
__global__ void cast4_f32_bf16(const float* __restrict__ in, unsigned short* __restrict__ out, int n) {
  int i = (blockIdx.x * 256 + threadIdx.x) * 4;
  if (i >= n) return;
  float4 v = *(const float4*)(in + i);
  us4 o = { f2bf(v.x), f2bf(v.y), f2bf(v.z), f2bf(v.w) };
  *(us4*)(out + i) = o;
}

// ---------- kernel 2: transpose+cast W[K][N] f32 -> Wt[N][K] bf16 ----------
__global__ void transcast(const float* __restrict__ in, unsigned short* __restrict__ out, int K, int N) {
  __shared__ float t[32][33];
  int n0 = blockIdx.x * 32, k0 = blockIdx.y * 32;
  int tx = threadIdx.x, ty = threadIdx.y;
#pragma unroll
  for (int i = 0; i < 4; ++i)
    t[ty * 4 + i][tx] = in[(size_t)(k0 + ty * 4 + i) * N + n0 + tx];
  __syncthreads();
#pragma unroll
  for (int i = 0; i < 4; ++i)
    out[(size_t)(n0 + ty * 4 + i) * K + k0 + tx] = f2bf(t[tx][ty * 4 + i]);
}

// ---------- GEMM (NT): C[M][N] = A[M][1024] * Bt[N][1024]^T + bias ----------
// 128x128 tile, BK=32, 4 waves (2x2), 16x16x32 bf16 MFMA, global_load_lds staging (m97 structure)
template <int OUT_BF16>
__global__ __launch_bounds__(256) void gemm_nt(
    const unsigned short* __restrict__ A,
    const unsigned short* __restrict__ Bt,
    const float* __restrict__ bias,
    void* __restrict__ C, int M, int N)
{
  __shared__ __align__(16) unsigned short Asm[128 * 32];
  __shared__ __align__(16) unsigned short Bsm[128 * 32];
  int bm = blockIdx.x, bn = blockIdx.y;
  int t = threadIdx.x, w = t >> 6, l = t & 63;
  int wm = w >> 1, wn = w & 1;
  int g = l >> 4, ln = l & 15;

  const unsigned short* Ablk = A + (size_t)(bm * 128) * GK;
  const unsigned short* Bblk = Bt + (size_t)(bn * 128) * GK;

  f32x4 acc[4][4] = {};

  int r0 = (w << 4) + (l >> 2);      // staging row within chunk group
  int kc = (l & 3) * 8;              // staging k offset (elems)

  for (int kt = 0; kt < GK / 32; ++kt) {
    __syncthreads();
    int k0 = kt * 32 + kc;
    gload16(Ablk + (size_t)r0 * GK + k0,        Asm + w * 512);
    gload16(Ablk + (size_t)(r0 + 64) * GK + k0, Asm + (4 + w) * 512);
    gload16(Bblk + (size_t)r0 * GK + k0,        Bsm + w * 512);
    gload16(Bblk + (size_t)(r0 + 64) * GK + k0, Bsm + (4 + w) * 512);
    __syncthreads();

    short8 af[4], bf[4];
    int ar = wm * 64 + ln;
    int br = wn * 64 + ln;
    int kk = g * 8;
#pragma unroll
    for (int mt = 0; mt < 4; ++mt)
      af[mt] = *(const short8*)(Asm + (ar + mt * 16) * 32 + kk);
#pragma unroll
    for (int nt = 0; nt < 4; ++nt)
      bf[nt] = *(const short8*)(Bsm + (br + nt * 16) * 32 + kk);
#pragma unroll
    for (int mt = 0; mt < 4; ++mt)
#pragma unroll
      for (int nt = 0; nt < 4; ++nt)
        acc[mt][nt] = __builtin_amdgcn_mfma_f32_16x16x32_bf16(af[mt], bf[nt], acc[mt][nt], 0, 0, 0);
  }

  int rowb = bm * 128 + wm * 64 + (g << 2);
  int colb = bn * 128 + wn * 64 + ln;
#pragma unroll
  for (int nt = 0; nt < 4; ++nt) {
    int col = colb + nt * 16;
    float bv = bias[col];
#pragma unroll
    for (int mt = 0; mt < 4; ++mt) {
      int row = rowb + mt * 16;
#pragma unroll
      for (int r = 0; r < 4; ++r) {
        float v = acc[mt][nt][r] + bv;
        if (OUT_BF16) ((unsigned short*)C)[(size_t)(row + r) * N + col] = f2bf(v);
        else          ((float*)C)[(size_t)(row + r) * N + col] = v;
      }
    }
  }
}

// ---------- kernel: transpose V slice of qkv -> Vt[(b*16+h)*64 + d][S] ----------
__global__ void transpose_v(const unsigned short* __restrict__ qkvb, unsigned short* __restrict__ Vt) {
  __shared__ __align__(16) unsigned short tile[64][72];   // [s][d], padded
  int blk = blockIdx.x;              // (b*16+h)*16 + s_tile
  int st = blk & 15, bh = blk >> 4, h = bh & 15, b = bh >> 4;
  int t = threadIdx.x;
  int srow = t >> 2, c0 = (t & 3) * 2;

  const unsigned short* src = qkvb + (size_t)(b * 1024 + st * 64 + srow) * 3072 + 2048 + h * 64;
#pragma unroll
  for (int j = 0; j < 2; ++j)
    *(short8*)(&tile[srow][(c0 + j) * 8]) = *(const short8*)(src + (c0 + j) * 8);
  __syncthreads();

  int d = t >> 2;
  unsigned short* dst = Vt + (size_t)(bh * 64 + d) * 1024 + st * 64;
#pragma unroll
  for (int j = 0; j < 2; ++j) {
    int s0 = (c0 + j) * 8;
    short8 v;
#pragma unroll
    for (int i = 0; i < 8; ++i) v[i] = tile[s0 + i][d];
    *(short8*)(dst + s0) = v;
  }
}

// ---------- flash attention v3: shared double-buffered LDS staging via global_load_lds,
// paired q-tiles for uniform 17-iteration blocks, 1 barrier/iter, mask hoisted to diag tile.
// Grid: 1024 blocks; decode bh = blk & 127 so all 8 pair-blocks of one (b,h) hit one XCD's L2.
__global__ __launch_bounds__(256) void attn(
    const unsigned short* __restrict__ qkv,  // [8192][3072] bf16
    const unsigned short* __restrict__ Vt,   // [(b*16+h)*64 + d][1024] bf16
    unsigned short* __restrict__ Ob)         // [8192][1024] bf16
{
  __shared__ __align__(16) unsigned short Ksm[2][64 * 64];  // [key][d] swizzled chunks
  __shared__ __align__(16) unsigned short Vsm[2][64 * 64];  // [d][key] swizzled chunks
  __shared__ __align__(16) unsigned short Psm[4][16 * 64];  // per-wave P [qrow][key] swizzled

  int t = threadIdx.x, w = t >> 6, l = t & 63;
  int g = l >> 4, ln = l & 15;
  int blk = blockIdx.x;
  int bh = blk & 127, pb = blk >> 7;       // same bh -> same XCD (round-robin dispatch)
  int h = bh & 15, b = bh >> 4;

  const unsigned short* Kg = qkv + (size_t)(b * 1024) * 3072 + 1024 + h * 64;
  const unsigned short* Vg = Vt + (size_t)(bh * 64) * 1024;
  unsigned short* P = Psm[w];

  int jrow = l >> 3;          // row within an 8-row (1KB) chunk
  int jc   = l & 7;           // linear 16B chunk within row

  int cur = 0;

  // stage K/V tile kt into buffer buf: linear LDS dest, inverse-swizzled global source
  auto stage = [&](int buf, int kt) {
#pragma unroll
    for (int jj = 0; jj < 2; ++jj) {
      int j = 2 * w + jj;                  // 1KB chunk id 0..7 (8 rows each)
      int row = j * 8 + jrow;              // 0..63
      int sc = jc ^ (row & 7);             // pre-swizzled source chunk
      gload16(Kg + (size_t)(kt * 64 + row) * 3072 + sc * 8, (unsigned short*)Ksm[buf] + j * 512);
      gload16(Vg + (size_t)row * 1024 + kt * 64 + sc * 8,   (unsigned short*)Vsm[buf] + j * 512);
    }
  };

#pragma unroll
  for (int half = 0; half < 2; ++half) {
    int qt = half ? (15 - pb) : pb;        // 64-row q-tile; iters qt+1 -> total 17/block

    const unsigned short* qbase =
        qkv + (size_t)(b * 1024 + qt * 64 + w * 16 + ln) * 3072 + h * 64 + g * 8;
    short8 qf0 = *(const short8*)(qbase);
    short8 qf1 = *(const short8*)(qbase + 32);

    f32x4 acc_o[4] = {};
    float m_r[4], l_r[4];
#pragma unroll
    for (int r = 0; r < 4; ++r) { m_r[r] = -1.0e30f; l_r[r] = 0.f; }

    stage(cur, 0);
    __syncthreads();                        // implicit vmcnt(0) drain

    for (int kt = 0; kt <= qt; ++kt) {
      bool last = (kt == qt);
      if (!last) stage(cur ^ 1, kt + 1);    // prefetch next tile, overlaps compute below

      // S = Q K^T  (16 q rows x 64 keys, dh=64)
      const unsigned short* Kb = Ksm[cur];
      f32x4 s[4] = {};
#pragma unroll
      for (int nt = 0; nt < 4; ++nt) {
        int krow = nt * 16 + ln;
        short8 b0 = *(const short8*)(Kb + krow * 64 + ((g ^ (krow & 7)) * 8));
        short8 b1 = *(const short8*)(Kb + krow * 64 + (((4 + g) ^ (krow & 7)) * 8));
        s[nt] = __builtin_amdgcn_mfma_f32_16x16x32_bf16(qf0, b0, s[nt], 0, 0, 0);
        s[nt] = __builtin_amdgcn_mfma_f32_16x16x32_bf16(qf1, b1, s[nt], 0, 0, 0);
      }

      // causal mask only on the diagonal tile (raw-score domain; scale folded into exp)
      if (last) {
        int qrow = w * 16 + g * 4;
#pragma unroll
        for (int nt = 0; nt < 4; ++nt)
#pragma unroll
          for (int r = 0; r < 4; ++r)
            if (nt * 16 + ln > qrow + r) s[nt][r] = -1.0e9f;
      }

      // online softmax; row (g*4+r) spread over the 16 lanes of group g
#pragma unroll
      for (int r = 0; r < 4; ++r) {
        float mraw = fmaxf(fmaxf(s[0][r], s[1][r]), fmaxf(s[2][r], s[3][r]));
#pragma unroll
        for (int off = 8; off >= 1; off >>= 1) mraw = fmaxf(mraw, __shfl_xor(mraw, off));
        float mnew = fmaxf(m_r[r], mraw * 0.125f);
        float corr = __expf(m_r[r] - mnew);
        m_r[r] = mnew;
        float rs = 0.f;
#pragma unroll
        for (int nt = 0; nt < 4; ++nt) {
          float p = __expf(fmaf(s[nt][r], 0.125f, -mnew));   // exp(s/8 - m)
          s[nt][r] = p;
          rs += p;
        }
#pragma unroll
        for (int off = 8; off >= 1; off >>= 1) rs += __shfl_xor(rs, off);
        l_r[r] = fmaf(l_r[r], corr, rs);
#pragma unroll
        for (int nt = 0; nt < 4; ++nt) acc_o[nt][r] *= corr;
      }

      // P (bf16) -> per-wave swizzled LDS (wave-local), read back as A-frags
#pragma unroll
      for (int nt = 0; nt < 4; ++nt) {
        int col = nt * 16 + ln;
#pragma unroll
        for (int r = 0; r < 4; ++r) {
          int prow = g * 4 + r;
          P[prow * 64 + (((col >> 3) ^ (prow & 7)) * 8) + (col & 7)] = f2bf(s[nt][r]);
        }
      }
      short8 pa0 = *(const short8*)(P + ln * 64 + ((g ^ (ln & 7)) * 8));
      short8 pa1 = *(const short8*)(P + ln * 64 + (((4 + g) ^ (ln & 7)) * 8));

      // PV: B-frags from staged V^T tile
      const unsigned short* Vb = Vsm[cur];
#pragma unroll
      for (int nt = 0; nt < 4; ++nt) {
        int vrow = nt * 16 + ln;
        short8 vb0 = *(const short8*)(Vb + vrow * 64 + ((g ^ (vrow & 7)) * 8));
        short8 vb1 = *(const short8*)(Vb + vrow * 64 + (((4 + g) ^ (vrow & 7)) * 8));
        acc_o[nt] = __builtin_amdgcn_mfma_f32_16x16x32_bf16(pa0, vb0, acc_o[nt], 0, 0, 0);
        acc_o[nt] = __builtin_amdgcn_mfma_f32_16x16x32_bf16(pa1, vb1, acc_o[nt], 0, 0, 0);
      }

      __syncthreads();                      // drains prefetch vmcnt + releases buffers
      cur ^= 1;
    }

    // normalize + store
    float inv[4];
#pragma unroll
    for (int r = 0; r < 4; ++r) inv[r] = 1.0f / l_r[r];
    int orow = b * 1024 + qt * 64 + w * 16;
#pragma unroll
    for (int nt = 0; nt < 4; ++nt) {
      int col = h * 64 + nt * 16 + ln;
#pragma unroll
      for (int r = 0; r < 4; ++r)
        Ob[(size_t)(orow + g * 4 + r) * 1024 + col] = f2bf(acc_o[nt][r] * inv[r]);
    }
  }
}

// ---------- launcher ----------
extern "C" void kernel_launch(void* const* d_in, const int* in_sizes, int n_in,
                              void* d_out, int out_size, void* d_ws, size_t ws_size,
                              hipStream_t stream) {
  (void)in_sizes; (void)n_in; (void)out_size; (void)ws_size;
  const float* x    = (const float*)d_in[0];
  const float* Wqkv = (const float*)d_in[1];
  const float* bqkv = (const float*)d_in[2];
  const float* Wout = (const float*)d_in[3];
  const float* bout = (const float*)d_in[4];

  char* ws = (char*)d_ws;
  unsigned short* xb   = (unsigned short*)(ws);                 // 16 MB  [8192][1024]
  unsigned short* Wt1  = (unsigned short*)(ws + 16777216);      //  6 MB  [3072][1024]
  unsigned short* Wt2  = (unsigned short*)(ws + 23068672);      //  2 MB  [1024][1024]
  unsigned short* qkvb = (unsigned short*)(ws + 25165824);      // 50 MB  [8192][3072]
  unsigned short* Vt   = (unsigned short*)(ws + 75497472);      // 16 MB  [128*64][1024]
  unsigned short* Ob   = (unsigned short*)(ws + 92274688);      // 16 MB  [8192][1024]

  cast4_f32_bf16<<<8192, 256, 0, stream>>>(x, xb, 8192 * 1024);
  transcast<<<dim3(96, 32), dim3(32, 8), 0, stream>>>(Wqkv, Wt1, 1024, 3072);
  transcast<<<dim3(32, 32), dim3(32, 8), 0, stream>>>(Wout, Wt2, 1024, 1024);

  gemm_nt<1><<<dim3(64, 24), 256, 0, stream>>>(xb, Wt1, bqkv, qkvb, 8192, 3072);
  transpose_v<<<2048, 256, 0, stream>>>(qkvb, Vt);
  attn<<<1024, 256, 0, stream>>>(qkvb, Vt, Ob);
  gemm_nt<0><<<dim3(64, 8), 256, 0, stream>>>(Ob, Wt2, bout, (float*)d_out, 8192, 1024);
}

// Round 9
// 243.283 us; speedup vs baseline: 1.3068x; 1.0919x over previous
//
#include <hip/hip_runtime.h>
#include <hip/hip_bf16.h>

typedef __attribute__((ext_vector_type(8))) short short8;   // 8 x bf16 (4 VGPRs) MFMA frag
typedef __attribute__((ext_vector_type(4))) float f32x4;    // MFMA accumulator
typedef __attribute__((ext_vector_type(4))) unsigned short us4;

#define GK 1024   // K dim of both GEMMs (= word dim)

// fast base-2 exp on gfx950 (v_exp_f32). NOTE: __exp2f is CUDA-only and collides
// with glibc math.h macros under hipcc — use the amdgcn builtin instead.
#define EXP2F(x) __builtin_amdgcn_exp2f(x)

// ---------- helpers ----------
__device__ __forceinline__ unsigned short f2bf(float f) {       // RNE f32->bf16
  unsigned int u = __float_as_uint(f);
  u += 0x7fffu + ((u >> 16) & 1u);
  return (unsigned short)(u >> 16);
}

__device__ __forceinline__ void gload16(const void* g, void* lds_base /*wave-uniform*/) {
  __builtin_amdgcn_global_load_lds(
      (const __attribute__((address_space(1))) unsigned int*)g,
      (__attribute__((address_space(3))) unsigned int*)lds_base, 16, 0, 0);
}

// ---------- kernel 1: cast f32 -> bf16 (x) ----------
__global__ void cast4_f32_bf16(const float* __restrict__ in, unsigned short* __restrict__ out, int n) {
  int i = (blockIdx.x * 256 + threadIdx.x) * 4;
  if (i >= n) return;
  float4 v = *(const float4*)(in + i);
  us4 o = { f2bf(v.x), f2bf(v.y), f2bf(v.z), f2bf(v.w) };
  *(us4*)(out + i) = o;
}

// ---------- kernel 2: transpose+cast W[K][N] f32 -> Wt[N][K] bf16 ----------
__global__ void transcast(const float* __restrict__ in, unsigned short* __restrict__ out, int K, int N) {
  __shared__ float t[32][33];
  int n0 = blockIdx.x * 32, k0 = blockIdx.y * 32;
  int tx = threadIdx.x, ty = threadIdx.y;
#pragma unroll
  for (int i = 0; i < 4; ++i)
    t[ty * 4 + i][tx] = in[(size_t)(k0 + ty * 4 + i) * N + n0 + tx];
  __syncthreads();
#pragma unroll
  for (int i = 0; i < 4; ++i)
    out[(size_t)(n0 + ty * 4 + i) * K + k0 + tx] = f2bf(t[tx][ty * 4 + i]);
}

// ---------- GEMM (NT): C[M][N] = A[M][1024] * Bt[N][1024]^T + bias ----------
// 128x128 tile, BK=32, 4 waves (2x2), 16x16x32 bf16 MFMA, global_load_lds staging (m97 structure).
// Bijective 8-wide bm-supertile block remap: ~64 co-resident blocks cover an 8x8
// (bm,bn) supertile (A 2MB + B 2MB ~ L2-resident) instead of 64 bm x 1 bn (A 16MB).
template <int OUT_BF16>
__global__ __launch_bounds__(256) void gemm_nt(
    const unsigned short* __restrict__ A,
    const unsigned short* __restrict__ Bt,
    const float* __restrict__ bias,
    void* __restrict__ C, int M, int N)
{
  __shared__ __align__(16) unsigned short Asm[128 * 32];
  __shared__ __align__(16) unsigned short Bsm[128 * 32];

  // linear dispatch id -> (bm, bn) supertile remap (bijective: gridDim.x % 8 == 0)
  int flat = blockIdx.y * gridDim.x + blockIdx.x;
  int span = 8 * gridDim.y;                 // blocks per bm-stripe
  int stripe = flat / span;
  int r = flat - stripe * span;
  int bm = stripe * 8 + (r & 7);
  int bn = r >> 3;

  int t = threadIdx.x, w = t >> 6, l = t & 63;
  int wm = w >> 1, wn = w & 1;
  int g = l >> 4, ln = l & 15;

  const unsigned short* Ablk = A + (size_t)(bm * 128) * GK;
  const unsigned short* Bblk = Bt + (size_t)(bn * 128) * GK;

  f32x4 acc[4][4] = {};

  int r0 = (w << 4) + (l >> 2);      // staging row within chunk group
  int kc = (l & 3) * 8;              // staging k offset (elems)

  for (int kt = 0; kt < GK / 32; ++kt) {
    __syncthreads();
    int k0 = kt * 32 + kc;
    gload16(Ablk + (size_t)r0 * GK + k0,        Asm + w * 512);
    gload16(Ablk + (size_t)(r0 + 64) * GK + k0, Asm + (4 + w) * 512);
    gload16(Bblk + (size_t)r0 * GK + k0,        Bsm + w * 512);
    gload16(Bblk + (size_t)(r0 + 64) * GK + k0, Bsm + (4 + w) * 512);
    __syncthreads();

    short8 af[4], bf[4];
    int ar = wm * 64 + ln;
    int br = wn * 64 + ln;
    int kk = g * 8;
#pragma unroll
    for (int mt = 0; mt < 4; ++mt)
      af[mt] = *(const short8*)(Asm + (ar + mt * 16) * 32 + kk);
#pragma unroll
    for (int nt = 0; nt < 4; ++nt)
      bf[nt] = *(const short8*)(Bsm + (br + nt * 16) * 32 + kk);
#pragma unroll
    for (int mt = 0; mt < 4; ++mt)
#pragma unroll
      for (int nt = 0; nt < 4; ++nt)
        acc[mt][nt] = __builtin_amdgcn_mfma_f32_16x16x32_bf16(af[mt], bf[nt], acc[mt][nt], 0, 0, 0);
  }

  int rowb = bm * 128 + wm * 64 + (g << 2);
  int colb = bn * 128 + wn * 64 + ln;
#pragma unroll
  for (int nt = 0; nt < 4; ++nt) {
    int col = colb + nt * 16;
    float bv = bias[col];
#pragma unroll
    for (int mt = 0; mt < 4; ++mt) {
      int row = rowb + mt * 16;
#pragma unroll
      for (int r2 = 0; r2 < 4; ++r2) {
        float v = acc[mt][nt][r2] + bv;
        if (OUT_BF16) ((unsigned short*)C)[(size_t)(row + r2) * N + col] = f2bf(v);
        else          ((float*)C)[(size_t)(row + r2) * N + col] = v;
      }
    }
  }
}

// ---------- kernel: transpose V slice of qkv -> Vt[(b*16+h)*64 + d][S] ----------
__global__ void transpose_v(const unsigned short* __restrict__ qkvb, unsigned short* __restrict__ Vt) {
  __shared__ __align__(16) unsigned short tile[64][72];   // [s][d], padded
  int blk = blockIdx.x;              // (b*16+h)*16 + s_tile
  int st = blk & 15, bh = blk >> 4, h = bh & 15, b = bh >> 4;
  int t = threadIdx.x;
  int srow = t >> 2, c0 = (t & 3) * 2;

  const unsigned short* src = qkvb + (size_t)(b * 1024 + st * 64 + srow) * 3072 + 2048 + h * 64;
#pragma unroll
  for (int j = 0; j < 2; ++j)
    *(short8*)(&tile[srow][(c0 + j) * 8]) = *(const short8*)(src + (c0 + j) * 8);
  __syncthreads();

  int d = t >> 2;
  unsigned short* dst = Vt + (size_t)(bh * 64 + d) * 1024 + st * 64;
#pragma unroll
  for (int j = 0; j < 2; ++j) {
    int s0 = (c0 + j) * 8;
    short8 v;
#pragma unroll
    for (int i = 0; i < 8; ++i) v[i] = tile[s0 + i][d];
    *(short8*)(dst + s0) = v;
  }
}

// ---------- flash attention v4: swapped-operand MFMA (lane-local softmax rows) ----------
// mfma(K,Q) -> S^T: lane owns q-row ln, 16 of its 64 key scores. Row reduce = local tree
// + shfl_xor(16,32). mfma(V,P) -> O^T: acc col = q-row ln, so corr/l apply lane-locally.
// Staging / pairing / XCD decode / swizzles identical to v3.
__global__ __launch_bounds__(256) void attn(
    const unsigned short* __restrict__ qkv,  // [8192][3072] bf16
    const unsigned short* __restrict__ Vt,   // [(b*16+h)*64 + d][1024] bf16
    unsigned short* __restrict__ Ob)         // [8192][1024] bf16
{
  __shared__ __align__(16) unsigned short Ksm[2][64 * 64];  // [key][d] swizzled chunks
  __shared__ __align__(16) unsigned short Vsm[2][64 * 64];  // [d][key] swizzled chunks
  __shared__ __align__(16) unsigned short Psm[4][16 * 64];  // per-wave P [qrow][key] swizzled

  const float C1 = 0.18033688011112042f;    // 0.125 * log2(e)

  int t = threadIdx.x, w = t >> 6, l = t & 63;
  int g = l >> 4, ln = l & 15;
  int blk = blockIdx.x;
  int bh = blk & 127, pb = blk >> 7;        // same bh -> same XCD (round-robin dispatch)
  int h = bh & 15, b = bh >> 4;

  const unsigned short* Kg = qkv + (size_t)(b * 1024) * 3072 + 1024 + h * 64;
  const unsigned short* Vg = Vt + (size_t)(bh * 64) * 1024;
  unsigned short* P = Psm[w];

  int jrow = l >> 3;
  int jc   = l & 7;
  int cur = 0;

  auto stage = [&](int buf, int kt) {
#pragma unroll
    for (int jj = 0; jj < 2; ++jj) {
      int j = 2 * w + jj;
      int row = j * 8 + jrow;
      int sc = jc ^ (row & 7);
      gload16(Kg + (size_t)(kt * 64 + row) * 3072 + sc * 8, (unsigned short*)Ksm[buf] + j * 512);
      gload16(Vg + (size_t)row * 1024 + kt * 64 + sc * 8,   (unsigned short*)Vsm[buf] + j * 512);
    }
  };

  // P write slot (elements): row ln, keys nt*16+g*4..+3 -> chunk (nt*2+(g>>1))^(ln&7), half g&1
  int pwbase = ln * 64 + (g & 1) * 4;

#pragma unroll
  for (int half = 0; half < 2; ++half) {
    int qt = half ? (15 - pb) : pb;        // 64-row q-tile; iters qt+1 -> total 17/block

    const unsigned short* qbase =
        qkv + (size_t)(b * 1024 + qt * 64 + w * 16 + ln) * 3072 + h * 64 + g * 8;
    short8 qf0 = *(const short8*)(qbase);
    short8 qf1 = *(const short8*)(qbase + 32);

    f32x4 acc_o[4] = {};
    float m2 = -1.0e30f, lsum = 0.f;       // per-lane: row = qt*64 + w*16 + ln

    stage(cur, 0);
    __syncthreads();

    for (int kt = 0; kt <= qt; ++kt) {
      bool last = (kt == qt);
      if (!last) stage(cur ^ 1, kt + 1);    // prefetch next tile under compute

      // S^T = K Q^T: s[nt][r] = S[key = nt*16 + g*4 + r][qrow = ln]
      const unsigned short* Kb = Ksm[cur];
      f32x4 s[4] = {};
#pragma unroll
      for (int nt = 0; nt < 4; ++nt) {
        int krow = nt * 16 + ln;
        short8 k0 = *(const short8*)(Kb + krow * 64 + ((g ^ (krow & 7)) * 8));
        short8 k1 = *(const short8*)(Kb + krow * 64 + (((4 + g) ^ (krow & 7)) * 8));
        s[nt] = __builtin_amdgcn_mfma_f32_16x16x32_bf16(k0, qf0, s[nt], 0, 0, 0);
        s[nt] = __builtin_amdgcn_mfma_f32_16x16x32_bf16(k1, qf1, s[nt], 0, 0, 0);
      }

      // causal mask on diagonal tile: key (nt*16+g*4+r) > qrow (w*16+ln)
      if (last) {
        int qrow = w * 16 + ln;
#pragma unroll
        for (int nt = 0; nt < 4; ++nt)
#pragma unroll
          for (int r = 0; r < 4; ++r)
            if (nt * 16 + g * 4 + r > qrow) s[nt][r] = -1.0e9f;
      }

      // lane-local online softmax (row = ln), base-2 domain with folded 1/8 scale
      float mx0 = fmaxf(fmaxf(s[0][0], s[0][1]), fmaxf(s[0][2], s[0][3]));
      float mx1 = fmaxf(fmaxf(s[1][0], s[1][1]), fmaxf(s[1][2], s[1][3]));
      float mx2 = fmaxf(fmaxf(s[2][0], s[2][1]), fmaxf(s[2][2], s[2][3]));
      float mx3 = fmaxf(fmaxf(s[3][0], s[3][1]), fmaxf(s[3][2], s[3][3]));
      float mraw = fmaxf(fmaxf(mx0, mx1), fmaxf(mx2, mx3));
      mraw = fmaxf(mraw, __shfl_xor(mraw, 16));
      mraw = fmaxf(mraw, __shfl_xor(mraw, 32));
      float m2cand = mraw * C1;

      if (!__all(m2cand <= m2)) {           // T13 defer-max (exact): rescale only on growth
        float m2new = fmaxf(m2, m2cand);
        float corr = EXP2F(m2 - m2new);
        m2 = m2new;
        lsum *= corr;
#pragma unroll
        for (int nt = 0; nt < 4; ++nt)
#pragma unroll
          for (int r = 0; r < 4; ++r) acc_o[nt][r] *= corr;
      }

      float rs = 0.f;
#pragma unroll
      for (int nt = 0; nt < 4; ++nt)
#pragma unroll
        for (int r = 0; r < 4; ++r) {
          float p = EXP2F(fmaf(s[nt][r], C1, -m2));   // exp(s/8 - m)
          s[nt][r] = p;
          rs += p;
        }
      rs += __shfl_xor(rs, 16);
      rs += __shfl_xor(rs, 32);
      lsum += rs;

      // P -> per-wave swizzled LDS: one b64 per nt (4 contiguous keys of row ln)
#pragma unroll
      for (int nt = 0; nt < 4; ++nt) {
        us4 pk = { f2bf(s[nt][0]), f2bf(s[nt][1]), f2bf(s[nt][2]), f2bf(s[nt][3]) };
        *(us4*)(P + pwbase + (((nt * 2 + (g >> 1)) ^ (ln & 7)) * 8)) = pk;
      }
      short8 pa0 = *(const short8*)(P + ln * 64 + ((g ^ (ln & 7)) * 8));
      short8 pa1 = *(const short8*)(P + ln * 64 + (((4 + g) ^ (ln & 7)) * 8));

      // O^T = V^T P^T: acc_o[nt][r] = O[qrow=ln][d = nt*16 + g*4 + r]
      const unsigned short* Vb = Vsm[cur];
#pragma unroll
      for (int nt = 0; nt < 4; ++nt) {
        int vrow = nt * 16 + ln;
        short8 vb0 = *(const short8*)(Vb + vrow * 64 + ((g ^ (vrow & 7)) * 8));
        short8 vb1 = *(const short8*)(Vb + vrow * 64 + (((4 + g) ^ (vrow & 7)) * 8));
        acc_o[nt] = __builtin_amdgcn_mfma_f32_16x16x32_bf16(vb0, pa0, acc_o[nt], 0, 0, 0);
        acc_o[nt] = __builtin_amdgcn_mfma_f32_16x16x32_bf16(vb1, pa1, acc_o[nt], 0, 0, 0);
      }

      __syncthreads();                      // drains prefetch vmcnt + releases buffers
      cur ^= 1;
    }

    // normalize + store: lane owns row qt*64+w*16+ln, writes 4x 8B
    float inv = 1.0f / lsum;
    size_t orow = (size_t)(b * 1024 + qt * 64 + w * 16 + ln);
#pragma unroll
    for (int nt = 0; nt < 4; ++nt) {
      us4 o = { f2bf(acc_o[nt][0] * inv), f2bf(acc_o[nt][1] * inv),
                f2bf(acc_o[nt][2] * inv), f2bf(acc_o[nt][3] * inv) };
      *(us4*)(Ob + orow * 1024 + h * 64 + nt * 16 + g * 4) = o;
    }
  }
}

// ---------- launcher ----------
extern "C" void kernel_launch(void* const* d_in, const int* in_sizes, int n_in,
                              void* d_out, int out_size, void* d_ws, size_t ws_size,
                              hipStream_t stream) {
  (void)in_sizes; (void)n_in; (void)out_size; (void)ws_size;
  const float* x    = (const float*)d_in[0];
  const float* Wqkv = (const float*)d_in[1];
  const float* bqkv = (const float*)d_in[2];
  const float* Wout = (const float*)d_in[3];
  const float* bout = (const float*)d_in[4];

  char* ws = (char*)d_ws;
  unsigned short* xb   = (unsigned short*)(ws);                 // 16 MB  [8192][1024]
  unsigned short* Wt1  = (unsigned short*)(ws + 16777216);      //  6 MB  [3072][1024]
  unsigned short* Wt2  = (unsigned short*)(ws + 23068672);      //  2 MB  [1024][1024]
  unsigned short* qkvb = (unsigned short*)(ws + 25165824);      // 50 MB  [8192][3072]
  unsigned short* Vt   = (unsigned short*)(ws + 75497472);      // 16 MB  [128*64][1024]
  unsigned short* Ob   = (unsigned short*)(ws + 92274688);      // 16 MB  [8192][1024]

  cast4_f32_bf16<<<8192, 256, 0, stream>>>(x, xb, 8192 * 1024);
  transcast<<<dim3(96, 32), dim3(32, 8), 0, stream>>>(Wqkv, Wt1, 1024, 3072);
  transcast<<<dim3(32, 32), dim3(32, 8), 0, stream>>>(Wout, Wt2, 1024, 1024);

  gemm_nt<1><<<dim3(64, 24), 256, 0, stream>>>(xb, Wt1, bqkv, qkvb, 8192, 3072);
  transpose_v<<<2048, 256, 0, stream>>>(qkvb, Vt);
  attn<<<1024, 256, 0, stream>>>(qkvb, Vt, Ob);
  gemm_nt<0><<<dim3(64, 8), 256, 0, stream>>>(Ob, Wt2, bout, (float*)d_out, 8192, 1024);
}

// Round 11
// 238.342 us; speedup vs baseline: 1.3339x; 1.0207x over previous
//
#include <hip/hip_runtime.h>
#include <hip/hip_bf16.h>

typedef __attribute__((ext_vector_type(8))) short short8;   // 8 x bf16 (4 VGPRs) MFMA frag
typedef __attribute__((ext_vector_type(4))) float f32x4;    // MFMA accumulator
typedef __attribute__((ext_vector_type(4))) unsigned short us4;

#define GK 1024   // K dim of both GEMMs (= word dim)

// fast base-2 exp on gfx950 (v_exp_f32). __exp2f is CUDA-only (glibc macro collision).
#define EXP2F(x) __builtin_amdgcn_exp2f(x)

// ---------- helpers ----------
__device__ __forceinline__ unsigned short f2bf(float f) {       // RNE f32->bf16
  unsigned int u = __float_as_uint(f);
  u += 0x7fffu + ((u >> 16) & 1u);
  return (unsigned short)(u >> 16);
}

__device__ __forceinline__ void gload16(const void* g, void* lds_base /*wave-uniform*/) {
  __builtin_amdgcn_global_load_lds(
      (const __attribute__((address_space(1))) unsigned int*)g,
      (__attribute__((address_space(3))) unsigned int*)lds_base, 16, 0, 0);
}

// ---------- kernel 1: cast f32 -> bf16 (x) ----------
__global__ void cast4_f32_bf16(const float* __restrict__ in, unsigned short* __restrict__ out, int n) {
  int i = (blockIdx.x * 256 + threadIdx.x) * 4;
  if (i >= n) return;
  float4 v = *(const float4*)(in + i);
  us4 o = { f2bf(v.x), f2bf(v.y), f2bf(v.z), f2bf(v.w) };
  *(us4*)(out + i) = o;
}

// ---------- kernel 2: transpose+cast W[K][N] f32 -> Wt[N][K] bf16 ----------
__global__ void transcast(const float* __restrict__ in, unsigned short* __restrict__ out, int K, int N) {
  __shared__ float t[32][33];
  int n0 = blockIdx.x * 32, k0 = blockIdx.y * 32;
  int tx = threadIdx.x, ty = threadIdx.y;
#pragma unroll
  for (int i = 0; i < 4; ++i)
    t[ty * 4 + i][tx] = in[(size_t)(k0 + ty * 4 + i) * N + n0 + tx];
  __syncthreads();
#pragma unroll
  for (int i = 0; i < 4; ++i)
    out[(size_t)(n0 + ty * 4 + i) * K + k0 + tx] = f2bf(t[tx][ty * 4 + i]);
}

// ---------- GEMM (NT): C[M][N] = A[M][1024] * Bt[N][1024]^T + bias ----------
// 128x128 tile, BK=64 (2 barriers per 64-K slab = half the drains of BK=32),
// 4 waves (2x2), 16x16x32 bf16 MFMA, global_load_lds staging.
// LDS rows are 128B: XOR-swizzle chunk ^ (row&7) via pre-swizzled global source
// (linear LDS dest, rule 21) + matching read XOR -> conflict-free ds_read_b128
// (same pattern measured 0-conflict in attn). Bijective 8-wide bm-supertile remap.
template <int OUT_BF16>
__global__ __launch_bounds__(256) void gemm_nt(
    const unsigned short* __restrict__ A,
    const unsigned short* __restrict__ Bt,
    const float* __restrict__ bias,
    void* __restrict__ C, int M, int N)
{
  __shared__ __align__(16) unsigned short Asm[128 * 64];
  __shared__ __align__(16) unsigned short Bsm[128 * 64];

  // linear dispatch id -> (bm, bn) supertile remap (bijective: gridDim.x % 8 == 0)
  int flat = blockIdx.y * gridDim.x + blockIdx.x;
  int span = 8 * gridDim.y;                 // blocks per bm-stripe
  int stripe = flat / span;
  int r = flat - stripe * span;
  int bm = stripe * 8 + (r & 7);
  int bn = r >> 3;

  int t = threadIdx.x, w = t >> 6, l = t & 63;
  int wm = w >> 1, wn = w & 1;
  int g = l >> 4, ln = l & 15;

  const unsigned short* Ablk = A + (size_t)(bm * 128) * GK;
  const unsigned short* Bblk = Bt + (size_t)(bn * 128) * GK;

  f32x4 acc[4][4] = {};

  // staging: chunk = 8 rows x 64 cols = 1KB; wave w covers chunks w+4j, j=0..3.
  // lane l -> row_in_chunk l>>3, dest col slot (l&7); source col pre-swizzled by row&7 = l>>3.
  int srow_in = l >> 3;                       // 0..7
  int scol = (((l & 7) ^ (l >> 3)) * 8);      // swizzled source col (elems)
  int swA = ln & 7;                           // read-side row&7 (lane-constant: rows = wm*64+ln+16*mt)

  for (int kt = 0; kt < GK / 64; ++kt) {
    __syncthreads();
    int k0 = kt * 64 + scol;
#pragma unroll
    for (int j = 0; j < 4; ++j) {
      int chunk = w + 4 * j;                  // 0..15
      int row = chunk * 8 + srow_in;          // 0..127
      gload16(Ablk + (size_t)row * GK + k0, Asm + chunk * 512);
      gload16(Bblk + (size_t)row * GK + k0, Bsm + chunk * 512);
    }
    __syncthreads();

#pragma unroll
    for (int ks = 0; ks < 2; ++ks) {
      int pc = ((ks * 4 + g) ^ swA) * 8;      // physical 16B slot within the 64-elem row
      short8 af[4], bf[4];
#pragma unroll
      for (int mt = 0; mt < 4; ++mt) {
        int row = wm * 64 + ln + mt * 16;
        af[mt] = *(const short8*)(Asm + row * 64 + pc);
      }
#pragma unroll
      for (int nt = 0; nt < 4; ++nt) {
        int row = wn * 64 + ln + nt * 16;
        bf[nt] = *(const short8*)(Bsm + row * 64 + pc);
      }
#pragma unroll
      for (int mt = 0; mt < 4; ++mt)
#pragma unroll
        for (int nt = 0; nt < 4; ++nt)
          acc[mt][nt] = __builtin_amdgcn_mfma_f32_16x16x32_bf16(af[mt], bf[nt], acc[mt][nt], 0, 0, 0);
    }
  }

  int rowb = bm * 128 + wm * 64 + (g << 2);
  int colb = bn * 128 + wn * 64 + ln;
#pragma unroll
  for (int nt = 0; nt < 4; ++nt) {
    int col = colb + nt * 16;
    float bv = bias[col];
#pragma unroll
    for (int mt = 0; mt < 4; ++mt) {
      int row = rowb + mt * 16;
#pragma unroll
      for (int r2 = 0; r2 < 4; ++r2) {
        float v = acc[mt][nt][r2] + bv;
        if (OUT_BF16) ((unsigned short*)C)[(size_t)(row + r2) * N + col] = f2bf(v);
        else          ((float*)C)[(size_t)(row + r2) * N + col] = v;
      }
    }
  }
}

// ---------- kernel: transpose V slice of qkv -> Vt[(b*16+h)*64 + d][S] ----------
__global__ void transpose_v(const unsigned short* __restrict__ qkvb, unsigned short* __restrict__ Vt) {
  __shared__ __align__(16) unsigned short tile[64][72];   // [s][d], padded
  int blk = blockIdx.x;              // (b*16+h)*16 + s_tile
  int st = blk & 15, bh = blk >> 4, h = bh & 15, b = bh >> 4;
  int t = threadIdx.x;
  int srow = t >> 2, c0 = (t & 3) * 2;

  const unsigned short* src = qkvb + (size_t)(b * 1024 + st * 64 + srow) * 3072 + 2048 + h * 64;
#pragma unroll
  for (int j = 0; j < 2; ++j)
    *(short8*)(&tile[srow][(c0 + j) * 8]) = *(const short8*)(src + (c0 + j) * 8);
  __syncthreads();

  int d = t >> 2;
  unsigned short* dst = Vt + (size_t)(bh * 64 + d) * 1024 + st * 64;
#pragma unroll
  for (int j = 0; j < 2; ++j) {
    int s0 = (c0 + j) * 8;
    short8 v;
#pragma unroll
    for (int i = 0; i < 8; ++i) v[i] = tile[s0 + i][d];
    *(short8*)(dst + s0) = v;
  }
}

// ---------- flash attention v4: swapped-operand MFMA (lane-local softmax rows) ----------
__global__ __launch_bounds__(256) void attn(
    const unsigned short* __restrict__ qkv,  // [8192][3072] bf16
    const unsigned short* __restrict__ Vt,   // [(b*16+h)*64 + d][1024] bf16
    unsigned short* __restrict__ Ob)         // [8192][1024] bf16
{
  __shared__ __align__(16) unsigned short Ksm[2][64 * 64];  // [key][d] swizzled chunks
  __shared__ __align__(16) unsigned short Vsm[2][64 * 64];  // [d][key] swizzled chunks
  __shared__ __align__(16) unsigned short Psm[4][16 * 64];  // per-wave P [qrow][key] swizzled

  const float C1 = 0.18033688011112042f;    // 0.125 * log2(e)

  int t = threadIdx.x, w = t >> 6, l = t & 63;
  int g = l >> 4, ln = l & 15;
  int blk = blockIdx.x;
  int bh = blk & 127, pb = blk >> 7;        // same bh -> same XCD (round-robin dispatch)
  int h = bh & 15, b = bh >> 4;

  const unsigned short* Kg = qkv + (size_t)(b * 1024) * 3072 + 1024 + h * 64;
  const unsigned short* Vg = Vt + (size_t)(bh * 64) * 1024;
  unsigned short* P = Psm[w];

  int jrow = l >> 3;
  int jc   = l & 7;
  int cur = 0;

  auto stage = [&](int buf, int kt) {
#pragma unroll
    for (int jj = 0; jj < 2; ++jj) {
      int j = 2 * w + jj;
      int row = j * 8 + jrow;
      int sc = jc ^ (row & 7);
      gload16(Kg + (size_t)(kt * 64 + row) * 3072 + sc * 8, (unsigned short*)Ksm[buf] + j * 512);
      gload16(Vg + (size_t)row * 1024 + kt * 64 + sc * 8,   (unsigned short*)Vsm[buf] + j * 512);
    }
  };

  // P write slot (elements): row ln, keys nt*16+g*4..+3 -> chunk (nt*2+(g>>1))^(ln&7), half g&1
  int pwbase = ln * 64 + (g & 1) * 4;

#pragma unroll
  for (int half = 0; half < 2; ++half) {
    int qt = half ? (15 - pb) : pb;        // 64-row q-tile; iters qt+1 -> total 17/block

    const unsigned short* qbase =
        qkv + (size_t)(b * 1024 + qt * 64 + w * 16 + ln) * 3072 + h * 64 + g * 8;
    short8 qf0 = *(const short8*)(qbase);
    short8 qf1 = *(const short8*)(qbase + 32);

    f32x4 acc_o[4] = {};
    float m2 = -1.0e30f, lsum = 0.f;       // per-lane: row = qt*64 + w*16 + ln

    stage(cur, 0);
    __syncthreads();

    for (int kt = 0; kt <= qt; ++kt) {
      bool last = (kt == qt);
      if (!last) stage(cur ^ 1, kt + 1);    // prefetch next tile under compute

      // S^T = K Q^T: s[nt][r] = S[key = nt*16 + g*4 + r][qrow = ln]
      const unsigned short* Kb = Ksm[cur];
      f32x4 s[4] = {};
#pragma unroll
      for (int nt = 0; nt < 4; ++nt) {
        int krow = nt * 16 + ln;
        short8 k0 = *(const short8*)(Kb + krow * 64 + ((g ^ (krow & 7)) * 8));
        short8 k1 = *(const short8*)(Kb + krow * 64 + (((4 + g) ^ (krow & 7)) * 8));
        s[nt] = __builtin_amdgcn_mfma_f32_16x16x32_bf16(k0, qf0, s[nt], 0, 0, 0);
        s[nt] = __builtin_amdgcn_mfma_f32_16x16x32_bf16(k1, qf1, s[nt], 0, 0, 0);
      }

      // causal mask on diagonal tile: key (nt*16+g*4+r) > qrow (w*16+ln)
      if (last) {
        int qrow = w * 16 + ln;
#pragma unroll
        for (int nt = 0; nt < 4; ++nt)
#pragma unroll
          for (int r = 0; r < 4; ++r)
            if (nt * 16 + g * 4 + r > qrow) s[nt][r] = -1.0e9f;
      }

      // lane-local online softmax (row = ln), base-2 domain with folded 1/8 scale
      float mx0 = fmaxf(fmaxf(s[0][0], s[0][1]), fmaxf(s[0][2], s[0][3]));
      float mx1 = fmaxf(fmaxf(s[1][0], s[1][1]), fmaxf(s[1][2], s[1][3]));
      float mx2 = fmaxf(fmaxf(s[2][0], s[2][1]), fmaxf(s[2][2], s[2][3]));
      float mx3 = fmaxf(fmaxf(s[3][0], s[3][1]), fmaxf(s[3][2], s[3][3]));
      float mraw = fmaxf(fmaxf(mx0, mx1), fmaxf(mx2, mx3));
      mraw = fmaxf(mraw, __shfl_xor(mraw, 16));
      mraw = fmaxf(mraw, __shfl_xor(mraw, 32));
      float m2cand = mraw * C1;

      if (!__all(m2cand <= m2)) {           // T13 defer-max (exact): rescale only on growth
        float m2new = fmaxf(m2, m2cand);
        float corr = EXP2F(m2 - m2new);
        m2 = m2new;
        lsum *= corr;
#pragma unroll
        for (int nt = 0; nt < 4; ++nt)
#pragma unroll
          for (int r = 0; r < 4; ++r) acc_o[nt][r] *= corr;
      }

      float rs = 0.f;
#pragma unroll
      for (int nt = 0; nt < 4; ++nt)
#pragma unroll
        for (int r = 0; r < 4; ++r) {
          float p = EXP2F(fmaf(s[nt][r], C1, -m2));   // exp(s/8 - m)
          s[nt][r] = p;
          rs += p;
        }
      rs += __shfl_xor(rs, 16);
      rs += __shfl_xor(rs, 32);
      lsum += rs;

      // P -> per-wave swizzled LDS: one b64 per nt (4 contiguous keys of row ln)
#pragma unroll
      for (int nt = 0; nt < 4; ++nt) {
        us4 pk = { f2bf(s[nt][0]), f2bf(s[nt][1]), f2bf(s[nt][2]), f2bf(s[nt][3]) };
        *(us4*)(P + pwbase + (((nt * 2 + (g >> 1)) ^ (ln & 7)) * 8)) = pk;
      }
      short8 pa0 = *(const short8*)(P + ln * 64 + ((g ^ (ln & 7)) * 8));
      short8 pa1 = *(const short8*)(P + ln * 64 + (((4 + g) ^ (ln & 7)) * 8));

      // O^T = V^T P^T: acc_o[nt][r] = O[qrow=ln][d = nt*16 + g*4 + r]
      const unsigned short* Vb = Vsm[cur];
#pragma unroll
      for (int nt = 0; nt < 4; ++nt) {
        int vrow = nt * 16 + ln;
        short8 vb0 = *(const short8*)(Vb + vrow * 64 + ((g ^ (vrow & 7)) * 8));
        short8 vb1 = *(const short8*)(Vb + vrow * 64 + (((4 + g) ^ (vrow & 7)) * 8));
        acc_o[nt] = __builtin_amdgcn_mfma_f32_16x16x32_bf16(vb0, pa0, acc_o[nt], 0, 0, 0);
        acc_o[nt] = __builtin_amdgcn_mfma_f32_16x16x32_bf16(vb1, pa1, acc_o[nt], 0, 0, 0);
      }

      __syncthreads();                      // drains prefetch vmcnt + releases buffers
      cur ^= 1;
    }

    // normalize + store: lane owns row qt*64+w*16+ln, writes 4x 8B
    float inv = 1.0f / lsum;
    size_t orow = (size_t)(b * 1024 + qt * 64 + w * 16 + ln);
#pragma unroll
    for (int nt = 0; nt < 4; ++nt) {
      us4 o = { f2bf(acc_o[nt][0] * inv), f2bf(acc_o[nt][1] * inv),
                f2bf(acc_o[nt][2] * inv), f2bf(acc_o[nt][3] * inv) };
      *(us4*)(Ob + orow * 1024 + h * 64 + nt * 16 + g * 4) = o;
    }
  }
}

// ---------- launcher ----------
extern "C" void kernel_launch(void* const* d_in, const int* in_sizes, int n_in,
                              void* d_out, int out_size, void* d_ws, size_t ws_size,
                              hipStream_t stream) {
  (void)in_sizes; (void)n_in; (void)out_size; (void)ws_size;
  const float* x    = (const float*)d_in[0];
  const float* Wqkv = (const float*)d_in[1];
  const float* bqkv = (const float*)d_in[2];
  const float* Wout = (const float*)d_in[3];
  const float* bout = (const float*)d_in[4];

  char* ws = (char*)d_ws;
  unsigned short* xb   = (unsigned short*)(ws);                 // 16 MB  [8192][1024]
  unsigned short* Wt1  = (unsigned short*)(ws + 16777216);      //  6 MB  [3072][1024]
  unsigned short* Wt2  = (unsigned short*)(ws + 23068672);      //  2 MB  [1024][1024]
  unsigned short* qkvb = (unsigned short*)(ws + 25165824);      // 50 MB  [8192][3072]
  unsigned short* Vt   = (unsigned short*)(ws + 75497472);      // 16 MB  [128*64][1024]
  unsigned short* Ob   = (unsigned short*)(ws + 92274688);      // 16 MB  [8192][1024]

  cast4_f32_bf16<<<8192, 256, 0, stream>>>(x, xb, 8192 * 1024);
  transcast<<<dim3(96, 32), dim3(32, 8), 0, stream>>>(Wqkv, Wt1, 1024, 3072);
  transcast<<<dim3(32, 32), dim3(32, 8), 0, stream>>>(Wout, Wt2, 1024, 1024);

  gemm_nt<1><<<dim3(64, 24), 256, 0, stream>>>(xb, Wt1, bqkv, qkvb, 8192, 3072);
  transpose_v<<<2048, 256, 0, stream>>>(qkvb, Vt);
  attn<<<1024, 256, 0, stream>>>(qkvb, Vt, Ob);
  gemm_nt<0><<<dim3(64, 8), 256, 0, stream>>>(Ob, Wt2, bout, (float*)d_out, 8192, 1024);
}